// Round 1
// baseline (54904.248 us; speedup 1.0000x reference)
//
#include <hip/hip_runtime.h>
#include <hip/hip_fp16.h>

// ---------------------------------------------------------------------------
// LSTM autoencoder (B=128,S=512,I=128,H=512), persistent-RNN design:
//  - prep: x -> fp16 [t][b][i], bsum = b_ih+b_hh per layer, W_lin -> fp16
//  - weff: W_eff = W_ih_de0 @ W_lin  (folds closed-loop pred into de0)
//  - persistent cooperative kernel: 256 wgs x 512 thr, weights LDS-resident.
//    Each wg owns 8 h-columns (32 gate cols) x 32 batch rows. Rounds are
//    gated by monotone counters (64 producers each), relaxed-poll + agent
//    acquire/release fences. Encoder L0/L1 interleaved with LAG to hide
//    flag latency; decoder de0/de1 strictly chained.
//  - pred GEMM: preds[b][t][i] = h1_store[t][b][:] @ W_lin^T  (parallel)
// ---------------------------------------------------------------------------

#define DEVINL __device__ __forceinline__

typedef _Float16 f16;
typedef _Float16 f16x8 __attribute__((ext_vector_type(8)));
typedef float    f32x4 __attribute__((ext_vector_type(4)));

constexpr int B = 128, S = 512, I = 128, H = 512, G4 = 4 * H; // G4 = 2048

// ---- d_ws layout (bytes) ----
constexpr size_t OFF_CNT    = 0;          // [4][512][4] u32          32768
constexpr size_t OFF_H1DBUF = 32768;      // [2][128][512] f16        262144
constexpr size_t OFF_C0     = 294912;     // [128][512] f32           262144
constexpr size_t OFF_C1     = 557056;     // [128][512] f32           262144
constexpr size_t OFF_H0ALL  = 819200;     // [513][128][512] f16      67239936
constexpr size_t OFF_DDBUF  = 68059136;   // [2][128][512] f16        262144
constexpr size_t OFF_H1ST   = 68321280;   // [512][128][512] f16      67108864
constexpr size_t OFF_XF16   = 135430144;  // [512][128][128] f16      16777216
constexpr size_t OFF_WLIN16 = 152207360;  // [128][512] f16           131072
constexpr size_t OFF_BSUM   = 152338432;  // [4][2048] f32            32768
constexpr size_t OFF_WEFF   = 152371200;  // [2048][512] f32          4194304
constexpr size_t WS_NEED    = 156565504;
constexpr size_t ZERO_BYTES = 950272;     // cnt + h1dbuf + c0 + c1 + h0_all slot0

// ---- LDS layout inside persistent kernel ----
constexpr int LDS_L0   = 0;       // enc L0 weights  (K=640)  40960 B
constexpr int LDS_L1   = 40960;   // enc L1 weights  (K=1024) 65536 B
constexpr int LDS_D0   = 0;       // dec de0 weights (K=1024) 65536 B
constexpr int LDS_D1   = 65536;   // dec de1 weights (K=1024) 65536 B
constexpr int LDS_SCR  = 131072;  // 4 x [16][16] f32 partial tiles  4096 B
constexpr int LDS_GB   = 135168;  // [32][33] f32 gate exchange      4224 B
constexpr int SMEM_BYTES = 139392;

// ===========================================================================
// prep: x transpose-convert, W_lin convert, bias sums
// ===========================================================================
__global__ void prep_kernel(const float* __restrict__ x,
                            const float* b0a, const float* b0b,
                            const float* b1a, const float* b1b,
                            const float* b2a, const float* b2b,
                            const float* b3a, const float* b3b,
                            const float* __restrict__ wlin, char* ws) {
    f16*   xf = (f16*)(ws + OFF_XF16);
    f16*   wl = (f16*)(ws + OFF_WLIN16);
    float* bs = (float*)(ws + OFF_BSUM);
    int tid = blockIdx.x * blockDim.x + threadIdx.x;
    int nth = gridDim.x * blockDim.x;
    for (int idx = tid; idx < S * B * I; idx += nth) {
        int i = idx & 127, b = (idx >> 7) & 127, t = idx >> 14;
        xf[idx] = (f16)x[((size_t)b * S + t) * I + i];   // [t][b][i] <- [b][t][i]
    }
    for (int idx = tid; idx < I * H; idx += nth) wl[idx] = (f16)wlin[idx];
    for (int idx = tid; idx < G4; idx += nth) {
        bs[idx]          = b0a[idx] + b0b[idx];
        bs[G4 + idx]     = b1a[idx] + b1b[idx];
        bs[2 * G4 + idx] = b2a[idx] + b2b[idx];
        bs[3 * G4 + idx] = b3a[idx] + b3b[idx];
    }
}

// ===========================================================================
// W_eff = W_ih_de0 [2048,128] @ W_lin [128,512]  -> [2048,512] fp32
// ===========================================================================
__global__ void weff_kernel(const float* __restrict__ wih_de0,
                            const float* __restrict__ wlin, char* ws) {
    float* weff = (float*)(ws + OFF_WEFF);
    int e  = blockIdx.x * 256 + threadIdx.x;  // grid 4096 -> exactly 2048*512
    int gc = e >> 9, k = e & 511;
    float acc = 0.f;
    for (int i = 0; i < I; ++i) acc += wih_de0[gc * I + i] * wlin[i * H + k];
    weff[e] = acc;
}

// ===========================================================================
// persistent kernel helpers
// ===========================================================================
struct PParams {
    const float *wih0, *whh0, *wih1, *whh1, *whh2, *wih3, *whh3;
    char* ws;
};

DEVINL void wait2(unsigned* a, unsigned* b) {
    if (threadIdx.x == 0) {
        if (a) while (__hip_atomic_load(a, __ATOMIC_RELAXED, __HIP_MEMORY_SCOPE_AGENT) < 64u) {}
        if (b) while (__hip_atomic_load(b, __ATOMIC_RELAXED, __HIP_MEMORY_SCOPE_AGENT) < 64u) {}
    }
    __syncthreads();
    __builtin_amdgcn_fence(__ATOMIC_ACQUIRE, "agent"); // invalidate stale cache before reads
}

DEVINL void arrive(unsigned* c) {
    __syncthreads();  // drains vmcnt: all wg stores are at L2
    if (threadIdx.x == 0) {
        __builtin_amdgcn_fence(__ATOMIC_RELEASE, "agent"); // writeback dirty L2
        __hip_atomic_fetch_add(c, 1u, __ATOMIC_RELAXED, __HIP_MEMORY_SCOPE_AGENT);
    }
}

// Fill LDS weight block: layout [ntile][K/32][lane64][8 f16] so the B-fragment
// ds_read_b128 is lane-linear (conflict-free). col c in [0,32): gate=c>>3,
// j=c&7 -> global gate row gcol = gate*512 + j0 + j.
template <int K, int SPLIT>
DEVINL void fill_w(f16* ldsW, const float* __restrict__ matA,
                   const float* __restrict__ matB, int j0) {
    for (int idx = threadIdx.x; idx < 32 * K; idx += 512) {
        int c = idx / K, k = idx - c * K;
        int gcol = ((c >> 3) << 9) + j0 + (c & 7);
        float w = (k < SPLIT) ? matA[(size_t)gcol * SPLIT + k]
                              : matB[(size_t)gcol * (K - SPLIT) + (k - SPLIT)];
        int nt = c >> 4, lane = (((k >> 3) & 3) << 4) | (c & 15);
        int ks = k >> 5, j = k & 7;
        ldsW[(((size_t)nt * (K / 32) + ks) * 64 + lane) * 8 + j] = (f16)w;
    }
}

// One recurrence round: gates[32 rows, 32 cols] = [actA|actB] @ Wslice^T + bias
// then LSTM cell update for this wg's (32 rows x 8 h-cols), h -> hdst (fp16).
// 8 waves: (m_t, n_t) output tile x k_h K-half; K-half partials reduced in LDS.
template <int K, int SPLIT>
DEVINL void lstm_round(const f16* __restrict__ actA, int strA,
                       const f16* __restrict__ actB, int strB, bool skipA,
                       const f16* __restrict__ ldsW, float bias,
                       float* scr, float* gb, float* __restrict__ c_buf,
                       f16* __restrict__ hdst, int m_idx, int j0) {
    const int tid = threadIdx.x;
    const int wv = tid >> 6, lane = tid & 63;
    const int m_t = (wv >> 1) & 1, n_t = wv & 1, k_h = wv >> 2;
    const int row = m_idx * 32 + m_t * 16 + (lane & 15);
    const int kk0 = (lane >> 4) * 8;
    f32x4 acc = (k_h == 0) ? (f32x4){bias, bias, bias, bias}
                           : (f32x4){0.f, 0.f, 0.f, 0.f};
    constexpr int KS = K / 32;
    const int ks0 = k_h * (KS / 2);
    const f16* pa = actA + (size_t)row * strA + kk0;
    const f16* pb = actB + (size_t)row * strB + kk0 - SPLIT;
#pragma unroll
    for (int s = 0; s < KS / 2; ++s) {
        int ks = ks0 + s;
        int kbase = ks * 32;
        if (kbase < SPLIT && skipA) continue;  // decoder t=0: inp0 == 0
        const f16* src = (kbase < SPLIT) ? pa : pb;
        f16x8 a = *(const f16x8*)(src + kbase);
        f16x8 b = *(const f16x8*)(ldsW + ((size_t)(n_t * KS + ks) * 64 + lane) * 8);
        acc = __builtin_amdgcn_mfma_f32_16x16x32_f16(a, b, acc, 0, 0, 0);
    }
    __syncthreads();
    {   // K-half reduction via LDS (col-major tiles so each lane's 4 are contiguous)
        float* sp = scr + (m_t * 2 + n_t) * 256;
        int col = lane & 15, r0 = (lane >> 4) * 4;
        if (k_h == 1) *(f32x4*)(sp + col * 16 + r0) = acc;
        __syncthreads();
        if (k_h == 0) {
            f32x4 p = *(const f32x4*)(sp + col * 16 + r0);
#pragma unroll
            for (int i = 0; i < 4; ++i)
                gb[(m_t * 16 + r0 + i) * 33 + n_t * 16 + col] = acc[i] + p[i];
        }
    }
    __syncthreads();
    if (tid < 256) {  // cell update: 32 rows x 8 h-cols
        int r = tid >> 3, jj = tid & 7;
        float gi = gb[r * 33 + jj],      gf = gb[r * 33 + 8 + jj];
        float gg = gb[r * 33 + 16 + jj], go = gb[r * 33 + 24 + jj];
        float si = 1.f / (1.f + __expf(-gi));
        float sf = 1.f / (1.f + __expf(-gf));
        float so = 1.f / (1.f + __expf(-go));
        float tg = tanhf(gg);
        int bb = m_idx * 32 + r, j = j0 + jj;
        size_t cix = (size_t)bb * H + j;
        float cn = sf * c_buf[cix] + si * tg;
        c_buf[cix] = cn;
        hdst[cix] = (f16)(so * tanhf(cn));
    }
}

// ===========================================================================
// the persistent cooperative kernel
// ===========================================================================
__global__ void __launch_bounds__(512, 1) lstm_persistent(PParams p) {
    extern __shared__ char smem[];
    char* ws = p.ws;
    unsigned* cnt = (unsigned*)(ws + OFF_CNT);
    f16*   h1db = (f16*)(ws + OFF_H1DBUF);
    float* c0   = (float*)(ws + OFF_C0);
    float* c1   = (float*)(ws + OFF_C1);
    f16*   h0all= (f16*)(ws + OFF_H0ALL);
    f16*   ddb  = (f16*)(ws + OFF_DDBUF);
    f16*   h1st = (f16*)(ws + OFF_H1ST);
    const f16*   xf   = (const f16*)(ws + OFF_XF16);
    const float* bs   = (const float*)(ws + OFF_BSUM);
    const float* weff = (const float*)(ws + OFF_WEFF);

    const int wg = blockIdx.x;
    const int m_idx = wg >> 6;        // 4 batch blocks of 32
    const int n_idx = wg & 63;        // 64 h-column slices of 8
    const int j0 = n_idx * 8;
    const int lane = threadIdx.x & 63, wv = threadIdx.x >> 6;
    const int n_t = wv & 1;
    // per-lane bias (used by k_h==0 waves): col c -> gate c>>3, j = c&7
    int ccol = n_t * 16 + (lane & 15);
    int goff = ((ccol >> 3) << 9) + j0 + (ccol & 7);
    float bias0 = bs[goff], bias1 = bs[G4 + goff];
    float bias2 = bs[2 * G4 + goff], bias3 = bs[3 * G4 + goff];

    f16* ldsL0 = (f16*)(smem + LDS_L0);
    f16* ldsL1 = (f16*)(smem + LDS_L1);
    f16* ldsD0 = (f16*)(smem + LDS_D0);
    f16* ldsD1 = (f16*)(smem + LDS_D1);
    float* scr = (float*)(smem + LDS_SCR);
    float* gb  = (float*)(smem + LDS_GB);

    unsigned* cL0 = cnt;                 // [512][4], h0(t) ready
    unsigned* cL1 = cnt + 512 * 4;       // h1_enc(t) ready
    unsigned* cD0 = cnt + 2 * 512 * 4;   // h0_de(t) ready
    unsigned* cD1 = cnt + 3 * 512 * 4;   // h1_de(t) ready

    fill_w<640, 128>(ldsL0, p.wih0, p.whh0, j0);
    fill_w<1024, 512>(ldsL1, p.wih1, p.whh1, j0);
    __syncthreads();

    // -------- encoder: L0 and L1 interleaved (L1 lags L0 by LAG steps) -----
    const int LAG = 3;
    for (int r = 0; r < 512 + LAG; ++r) {
        if (r < 512) {
            int t = r;
            wait2(t > 0 ? &cL0[(t - 1) * 4 + m_idx] : nullptr, nullptr);
            lstm_round<640, 128>(xf + (size_t)t * B * I, I,
                                 h0all + (size_t)t * B * H, H, false,
                                 ldsL0, bias0, scr, gb, c0,
                                 h0all + (size_t)(t + 1) * B * H, m_idx, j0);
            arrive(&cL0[t * 4 + m_idx]);
        }
        if (r >= LAG) {
            int t = r - LAG;
            wait2(&cL0[t * 4 + m_idx],
                  t > 0 ? &cL1[(t - 1) * 4 + m_idx] : nullptr);
            lstm_round<1024, 512>(h0all + (size_t)(t + 1) * B * H, H,
                                  h1db + (size_t)((t - 1) & 1) * B * H, H, false,
                                  ldsL1, bias1, scr, gb, c1,
                                  h1db + (size_t)(t & 1) * B * H, m_idx, j0);
            arrive(&cL1[t * 4 + m_idx]);
        }
    }

    // -------- decoder weight fill (own LDS; safe after our last enc round) --
    __syncthreads();
    fill_w<1024, 512>(ldsD0, weff, p.whh2, j0);
    fill_w<1024, 512>(ldsD1, p.wih3, p.whh3, j0);
    __syncthreads();

    // -------- decoder: closed loop, de0 -> de1 per step ---------------------
    for (int t = 0; t < 512; ++t) {
        if (t == 0) wait2(&cL1[511 * 4 + m_idx], nullptr);
        else        wait2(&cD0[(t - 1) * 4 + m_idx], &cD1[(t - 1) * 4 + m_idx]);
        // de0: A = h1(t-1) via W_eff (skipped at t=0: inp0 = 0), B = h0_de(t-1)
        lstm_round<1024, 512>(
            t == 0 ? (h1db + (size_t)1 * B * H) : (h1st + (size_t)(t - 1) * B * H), H,
            t == 0 ? (h0all + (size_t)512 * B * H) : (ddb + (size_t)((t - 1) & 1) * B * H), H,
            t == 0,
            ldsD0, bias2, scr, gb, c0,
            ddb + (size_t)(t & 1) * B * H, m_idx, j0);
        arrive(&cD0[t * 4 + m_idx]);

        wait2(&cD0[t * 4 + m_idx],
              t > 0 ? &cD1[(t - 1) * 4 + m_idx] : nullptr);
        // de1: A = h0_de(t), B = h1(t-1)
        lstm_round<1024, 512>(
            ddb + (size_t)(t & 1) * B * H, H,
            t == 0 ? (h1db + (size_t)1 * B * H) : (h1st + (size_t)(t - 1) * B * H), H,
            false,
            ldsD1, bias3, scr, gb, c1,
            h1st + (size_t)t * B * H, m_idx, j0);
        arrive(&cD1[t * 4 + m_idx]);
    }
}

// ===========================================================================
// final: preds[b][t][i] = sum_j h1_store[t][b][j] * W_lin[i][j]   (fp32 out)
// ===========================================================================
__global__ void __launch_bounds__(256) pred_kernel(const f16* __restrict__ h1s,
                                                   const f16* __restrict__ wl,
                                                   float* __restrict__ out) {
    int wg = blockIdx.x;                       // 1024 wgs x 64 rows
    int wv = threadIdx.x >> 6, lane = threadIdx.x & 63;
    int m0 = wg * 64 + wv * 16;
    int arow = m0 + (lane & 15);
    int kk0 = (lane >> 4) * 8;
    f32x4 acc[8];
#pragma unroll
    for (int n = 0; n < 8; ++n) acc[n] = (f32x4){0.f, 0.f, 0.f, 0.f};
#pragma unroll
    for (int ks = 0; ks < 16; ++ks) {
        f16x8 a = *(const f16x8*)(h1s + (size_t)arow * H + ks * 32 + kk0);
#pragma unroll
        for (int n = 0; n < 8; ++n) {
            f16x8 b = *(const f16x8*)(wl + (size_t)(n * 16 + (lane & 15)) * H + ks * 32 + kk0);
            acc[n] = __builtin_amdgcn_mfma_f32_16x16x32_f16(a, b, acc[n], 0, 0, 0);
        }
    }
    int col = lane & 15, r0 = (lane >> 4) * 4;
#pragma unroll
    for (int n = 0; n < 8; ++n)
#pragma unroll
        for (int i = 0; i < 4; ++i) {
            int m = m0 + r0 + i;
            int t = m >> 7, b = m & 127;
            out[((size_t)b * S + t) * I + n * 16 + col] = acc[n][i];
        }
}

// ===========================================================================
extern "C" void kernel_launch(void* const* d_in, const int* in_sizes, int n_in,
                              void* d_out, int out_size, void* d_ws, size_t ws_size,
                              hipStream_t stream) {
    (void)in_sizes; (void)n_in; (void)out_size; (void)ws_size;
    const float* x        = (const float*)d_in[0];
    const float* wih_en0  = (const float*)d_in[1];
    const float* whh_en0  = (const float*)d_in[2];
    const float* bih_en0  = (const float*)d_in[3];
    const float* bhh_en0  = (const float*)d_in[4];
    const float* wih_en1  = (const float*)d_in[5];
    const float* whh_en1  = (const float*)d_in[6];
    const float* bih_en1  = (const float*)d_in[7];
    const float* bhh_en1  = (const float*)d_in[8];
    const float* wih_de0  = (const float*)d_in[9];
    const float* whh_de0  = (const float*)d_in[10];
    const float* bih_de0  = (const float*)d_in[11];
    const float* bhh_de0  = (const float*)d_in[12];
    const float* wih_de1  = (const float*)d_in[13];
    const float* whh_de1  = (const float*)d_in[14];
    const float* bih_de1  = (const float*)d_in[15];
    const float* bhh_de1  = (const float*)d_in[16];
    const float* wlin     = (const float*)d_in[17];
    char* ws = (char*)d_ws;

    // zero: counters + h1 dbuf + c0 + c1 + h0_all slot 0 (one contiguous run)
    hipMemsetAsync(ws, 0, ZERO_BYTES, stream);
    prep_kernel<<<2048, 256, 0, stream>>>(x, bih_en0, bhh_en0, bih_en1, bhh_en1,
                                          bih_de0, bhh_de0, bih_de1, bhh_de1,
                                          wlin, ws);
    weff_kernel<<<4096, 256, 0, stream>>>(wih_de0, wlin, ws);

    hipFuncSetAttribute((const void*)lstm_persistent,
                        hipFuncAttributeMaxDynamicSharedMemorySize, SMEM_BYTES);
    PParams p{wih_en0, whh_en0, wih_en1, whh_en1, whh_de0, wih_de1, whh_de1, ws};
    void* args[] = {&p};
    hipLaunchCooperativeKernel((const void*)lstm_persistent, dim3(256), dim3(512),
                               args, SMEM_BYTES, stream);

    pred_kernel<<<1024, 256, 0, stream>>>((const f16*)(ws + OFF_H1ST),
                                          (const f16*)(ws + OFF_WLIN16),
                                          (float*)d_out);
}

// Round 2
// 13258.339 us; speedup vs baseline: 4.1411x; 4.1411x over previous
//
#include <hip/hip_runtime.h>
#include <hip/hip_fp16.h>

// ---------------------------------------------------------------------------
// LSTM autoencoder (B=128,S=512,I=128,H=512), persistent-RNN, round 2:
// FENCE-FREE cross-wg communication. All h-exchange data moves via explicit
// sc0|sc1 (MALL-coherent, write-through) inline-asm loads/stores; flags are
// relaxed agent atomics. No buffer_wbl2 / buffer_inv anywhere in the loop.
//  - 256 wgs x 512 thr, 4 groups (32 batch rows) x 64 wgs (8 h-cols each)
//  - weights LDS-resident; cell state in LDS (carries encoder -> decoder)
//  - waves: (m_t in 2) x (k_q in 4) K-split; each wave does both n-tiles
//  - encoder L0/L1 interleaved (LAG=3); decoder de0/de1 chained
//  - W_lin folded into de0 via W_eff; preds = one big GEMM at the end
// ---------------------------------------------------------------------------

#define DEVINL __device__ __forceinline__

typedef _Float16 f16;
typedef _Float16 f16x8 __attribute__((ext_vector_type(8)));
typedef float    f32x4 __attribute__((ext_vector_type(4)));

constexpr int B = 128, S = 512, I = 128, H = 512, G4 = 4 * H; // G4 = 2048

// ---- d_ws layout (bytes) ----
constexpr size_t OFF_CNT    = 0;          // [4][512][4] u32          32768
constexpr size_t OFF_H1DBUF = 32768;      // [2][128][512] f16        262144
constexpr size_t OFF_C0     = 294912;     // (unused now)             262144
constexpr size_t OFF_C1     = 557056;     // (unused now)             262144
constexpr size_t OFF_H0ALL  = 819200;     // [513][128][512] f16      67239936
constexpr size_t OFF_DDBUF  = 68059136;   // [2][128][512] f16        262144
constexpr size_t OFF_H1ST   = 68321280;   // [512][128][512] f16      67108864
constexpr size_t OFF_XF16   = 135430144;  // [512][128][128] f16      16777216
constexpr size_t OFF_WLIN16 = 152207360;  // [128][512] f16           131072
constexpr size_t OFF_BSUM   = 152338432;  // [4][2048] f32            32768
constexpr size_t OFF_WEFF   = 152371200;  // [2048][512] f32          4194304
constexpr size_t ZERO_BYTES = 950272;     // cnt + h1dbuf + (c0,c1) + h0_all slot0

// ---- LDS layout (single fixed layout, 152704 B total) ----
constexpr int LDS_L0   = 0;       // enc L0 weights (K=640)   40960
constexpr int LDS_L1   = 40960;   // enc L1 weights (K=1024)  65536
constexpr int LDS_D0   = 0;       // dec de0 weights (K=1024) 65536
constexpr int LDS_D1   = 65536;   // dec de1 weights (K=1024) 65536
constexpr int LDS_SCR  = 131072;  // 4 tiles x 3 parts x 320 f32 = 15360
constexpr int LDS_GB   = 146432;  // [32][33] f32 gate exchange 4224
constexpr int LDS_C0   = 150656;  // [256] f32 cell L0/de0      1024
constexpr int LDS_C1   = 151680;  // [256] f32 cell L1/de1      1024
constexpr int SMEM_BYTES = 152704;

// ---------------------------------------------------------------------------
// coherent (MALL) memory helpers — sc0 sc1 = bypass L1+L2, served at the
// coherence point. vmcnt bookkeeping is manual: ALL global ops inside a
// round are asm, drained with a single s_waitcnt vmcnt(0) + sched_barrier.
// ---------------------------------------------------------------------------
DEVINL void cload(f16x8& r, const f16* p) {   // coherent 16B load
    asm volatile("global_load_dwordx4 %0, %1, off sc0 sc1" : "=v"(r) : "v"(p));
}
DEVINL void ncload(f16x8& r, const f16* p) {  // cached load (read-only data)
    asm volatile("global_load_dwordx4 %0, %1, off" : "=v"(r) : "v"(p));
}
DEVINL void cstore_h(f16* p, unsigned v) {    // coherent 2B store
    asm volatile("global_store_short %0, %1, off sc0 sc1" :: "v"(p), "v"(v));
}
DEVINL void drain_vm() {
    asm volatile("s_waitcnt vmcnt(0)" ::: "memory");
    __builtin_amdgcn_sched_barrier(0);        // rule #18: pin uses after wait
}

// ===========================================================================
// prep: x transpose-convert, W_lin convert, bias sums
// ===========================================================================
__global__ void prep_kernel(const float* __restrict__ x,
                            const float* b0a, const float* b0b,
                            const float* b1a, const float* b1b,
                            const float* b2a, const float* b2b,
                            const float* b3a, const float* b3b,
                            const float* __restrict__ wlin, char* ws) {
    f16*   xf = (f16*)(ws + OFF_XF16);
    f16*   wl = (f16*)(ws + OFF_WLIN16);
    float* bs = (float*)(ws + OFF_BSUM);
    int tid = blockIdx.x * blockDim.x + threadIdx.x;
    int nth = gridDim.x * blockDim.x;
    for (int idx = tid; idx < S * B * I; idx += nth) {
        int i = idx & 127, b = (idx >> 7) & 127, t = idx >> 14;
        xf[idx] = (f16)x[((size_t)b * S + t) * I + i];   // [t][b][i] <- [b][t][i]
    }
    for (int idx = tid; idx < I * H; idx += nth) wl[idx] = (f16)wlin[idx];
    for (int idx = tid; idx < G4; idx += nth) {
        bs[idx]          = b0a[idx] + b0b[idx];
        bs[G4 + idx]     = b1a[idx] + b1b[idx];
        bs[2 * G4 + idx] = b2a[idx] + b2b[idx];
        bs[3 * G4 + idx] = b3a[idx] + b3b[idx];
    }
}

// ===========================================================================
// W_eff = W_ih_de0 [2048,128] @ W_lin [128,512]  -> [2048,512] fp32
// ===========================================================================
__global__ void weff_kernel(const float* __restrict__ wih_de0,
                            const float* __restrict__ wlin, char* ws) {
    float* weff = (float*)(ws + OFF_WEFF);
    int e  = blockIdx.x * 256 + threadIdx.x;  // grid 4096 -> exactly 2048*512
    int gc = e >> 9, k = e & 511;
    float acc = 0.f;
    for (int i = 0; i < I; ++i) acc += wih_de0[gc * I + i] * wlin[i * H + k];
    weff[e] = acc;
}

// ===========================================================================
// persistent kernel helpers
// ===========================================================================
struct PParams {
    const float *wih0, *whh0, *wih1, *whh1, *whh2, *wih3, *whh3;
    char* ws;
};

// Dual-wave poll (threads 0 and 64 -> different waves poll concurrently).
// NO acquire fence: consumer data loads are sc0|sc1 (MALL), coherent by
// construction; __syncthreads is the compiler/order barrier.
DEVINL void wait2(unsigned* a, unsigned* b) {
    if (threadIdx.x == 0 && a)
        while (__hip_atomic_load(a, __ATOMIC_RELAXED, __HIP_MEMORY_SCOPE_AGENT) < 64u) {}
    if (threadIdx.x == 64 && b)
        while (__hip_atomic_load(b, __ATOMIC_RELAXED, __HIP_MEMORY_SCOPE_AGENT) < 64u) {}
    __syncthreads();
}

// NO release fence: h-stores were sc0|sc1 write-through; per-wave vmcnt(0)
// retires them at the MALL, barrier joins all waves, then one flag add.
DEVINL void arrive(unsigned* c) {
    asm volatile("s_waitcnt vmcnt(0)" ::: "memory");
    __syncthreads();
    if (threadIdx.x == 0)
        __hip_atomic_fetch_add(c, 1u, __ATOMIC_RELAXED, __HIP_MEMORY_SCOPE_AGENT);
}

// Fill LDS weight block: layout [ntile][K/32][lane64][8 f16] so the B-fragment
// ds_read_b128 is lane-linear (conflict-free). col c in [0,32): gate=c>>3,
// j=c&7 -> global gate row gcol = gate*512 + j0 + j.
template <int K, int SPLIT>
DEVINL void fill_w(f16* ldsW, const float* __restrict__ matA,
                   const float* __restrict__ matB, int j0) {
    for (int idx = threadIdx.x; idx < 32 * K; idx += 512) {
        int c = idx / K, k = idx - c * K;
        int gcol = ((c >> 3) << 9) + j0 + (c & 7);
        float w = (k < SPLIT) ? matA[(size_t)gcol * SPLIT + k]
                              : matB[(size_t)gcol * (K - SPLIT) + (k - SPLIT)];
        int nt = c >> 4, lane = (((k >> 3) & 3) << 4) | (c & 15);
        int ks = k >> 5, j = k & 7;
        ldsW[(((size_t)nt * (K / 32) + ks) * 64 + lane) * 8 + j] = (f16)w;
    }
}

// One recurrence round. Waves: m_t = wv>>2 (16-row half), k_q = wv&3 (K
// quarter); each wave computes BOTH n-tiles (no redundant A loads).
// A-fragments batch-loaded via asm (coherent except NCA xf part), single
// vmcnt drain, MFMA, 4-way LDS reduction, gate exchange, cell update (LDS c),
// coherent h-slice store.
template <int K, int SPLIT, bool NCA>
DEVINL void lstm_round(const f16* __restrict__ actA, int strA,
                       const f16* __restrict__ actB, int strB, bool skipA,
                       const f16* __restrict__ ldsW, float biasN0, float biasN1,
                       float* scr, float* gb, float* c_lds,
                       f16* __restrict__ hdst, int m_idx, int j0) {
    const int tid = threadIdx.x;
    const int wv = tid >> 6, lane = tid & 63;
    const int m_t = wv >> 2, k_q = wv & 3;
    const int row = m_idx * 32 + m_t * 16 + (lane & 15);
    const int kk0 = (lane >> 4) * 8;
    constexpr int KS = K / 32;
    constexpr int SQ = KS / 4;
    const int ks0 = k_q * SQ;
    const f16* pa = actA + (size_t)row * strA + kk0;
    const f16* pb = actB + (size_t)row * strB + kk0 - SPLIT;

    f16x8 areg[SQ];
#pragma unroll
    for (int s = 0; s < SQ; ++s) {
        int kbase = (ks0 + s) * 32;
        if (kbase < SPLIT) {
            if (skipA) {
#pragma unroll
                for (int q = 0; q < 8; ++q) areg[s][q] = (f16)0;
            } else if (NCA) ncload(areg[s], pa + kbase);
            else            cload(areg[s], pa + kbase);
        } else cload(areg[s], pb + kbase);
    }
    drain_vm();

    f32x4 acc0 = (k_q == 0) ? (f32x4){biasN0, biasN0, biasN0, biasN0}
                            : (f32x4){0.f, 0.f, 0.f, 0.f};
    f32x4 acc1 = (k_q == 0) ? (f32x4){biasN1, biasN1, biasN1, biasN1}
                            : (f32x4){0.f, 0.f, 0.f, 0.f};
#pragma unroll
    for (int s = 0; s < SQ; ++s) {
        int ks = ks0 + s;
        f16x8 b0 = *(const f16x8*)(ldsW + (size_t)(ks * 64 + lane) * 8);
        f16x8 b1 = *(const f16x8*)(ldsW + (size_t)((KS + ks) * 64 + lane) * 8);
        acc0 = __builtin_amdgcn_mfma_f32_16x16x32_f16(areg[s], b0, acc0, 0, 0, 0);
        acc1 = __builtin_amdgcn_mfma_f32_16x16x32_f16(areg[s], b1, acc1, 0, 0, 0);
    }

    const int col = lane & 15, r0 = (lane >> 4) * 4;
    if (k_q) {  // partials -> scr (stride 20: 16B-aligned, 2-way banks = free)
        *(f32x4*)(scr + ((m_t * 2 + 0) * 3 + (k_q - 1)) * 320 + col * 20 + r0) = acc0;
        *(f32x4*)(scr + ((m_t * 2 + 1) * 3 + (k_q - 1)) * 320 + col * 20 + r0) = acc1;
    }
    __syncthreads();
    if (k_q == 0) {
#pragma unroll
        for (int part = 0; part < 3; ++part) {
            acc0 += *(const f32x4*)(scr + ((m_t * 2 + 0) * 3 + part) * 320 + col * 20 + r0);
            acc1 += *(const f32x4*)(scr + ((m_t * 2 + 1) * 3 + part) * 320 + col * 20 + r0);
        }
#pragma unroll
        for (int i = 0; i < 4; ++i) {
            gb[(m_t * 16 + r0 + i) * 33 + col]      = acc0[i];
            gb[(m_t * 16 + r0 + i) * 33 + 16 + col] = acc1[i];
        }
    }
    __syncthreads();
    if (tid < 256) {  // cell update: 32 rows x 8 h-cols, c in LDS
        int r = tid >> 3, jj = tid & 7;
        const float* grow = gb + r * 33;
        float gi = grow[jj], gf = grow[8 + jj], gg = grow[16 + jj], go = grow[24 + jj];
        float si = 1.f / (1.f + __expf(-gi));
        float sf = 1.f / (1.f + __expf(-gf));
        float so = 1.f / (1.f + __expf(-go));
        float tg = tanhf(gg);
        float cn = sf * c_lds[tid] + si * tg;
        c_lds[tid] = cn;
        union { f16 h; unsigned short u; } cvt;
        cvt.h = (f16)(so * tanhf(cn));
        cstore_h(hdst + (size_t)(m_idx * 32 + r) * H + j0 + jj, (unsigned)cvt.u);
    }
    // arrive (vmcnt drain + barrier + flag) done by caller
}

// ===========================================================================
// the persistent cooperative kernel
// ===========================================================================
__global__ void __launch_bounds__(512, 1) lstm_persistent(PParams p) {
    extern __shared__ char smem[];
    char* ws = p.ws;
    unsigned* cnt = (unsigned*)(ws + OFF_CNT);
    f16*   h1db = (f16*)(ws + OFF_H1DBUF);
    f16*   h0all= (f16*)(ws + OFF_H0ALL);
    f16*   ddb  = (f16*)(ws + OFF_DDBUF);
    f16*   h1st = (f16*)(ws + OFF_H1ST);
    const f16*   xf   = (const f16*)(ws + OFF_XF16);
    const float* bs   = (const float*)(ws + OFF_BSUM);
    const float* weff = (const float*)(ws + OFF_WEFF);

    const int wg = blockIdx.x;
    const int m_idx = wg >> 6;        // 4 batch blocks of 32
    const int n_idx = wg & 63;        // 64 h-column slices of 8
    const int j0 = n_idx * 8;
    const int lane = threadIdx.x & 63;
    // per-lane biases for both n-tiles (used by k_q==0 waves)
    int c0col = lane & 15, c1col = 16 + (lane & 15);
    int g0 = ((c0col >> 3) << 9) + j0 + (c0col & 7);
    int g1 = ((c1col >> 3) << 9) + j0 + (c1col & 7);
    float b0n0 = bs[g0],          b0n1 = bs[g1];
    float b1n0 = bs[G4 + g0],     b1n1 = bs[G4 + g1];
    float b2n0 = bs[2 * G4 + g0], b2n1 = bs[2 * G4 + g1];
    float b3n0 = bs[3 * G4 + g0], b3n1 = bs[3 * G4 + g1];

    f16* ldsL0 = (f16*)(smem + LDS_L0);
    f16* ldsL1 = (f16*)(smem + LDS_L1);
    f16* ldsD0 = (f16*)(smem + LDS_D0);
    f16* ldsD1 = (f16*)(smem + LDS_D1);
    float* scr = (float*)(smem + LDS_SCR);
    float* gb  = (float*)(smem + LDS_GB);
    float* c0l = (float*)(smem + LDS_C0);
    float* c1l = (float*)(smem + LDS_C1);

    unsigned* cL0 = cnt;                 // [512][4], h0(t) ready
    unsigned* cL1 = cnt + 512 * 4;       // h1_enc(t) ready
    unsigned* cD0 = cnt + 2 * 512 * 4;   // h0_de(t) ready
    unsigned* cD1 = cnt + 3 * 512 * 4;   // h1_de(t) ready

    if (threadIdx.x < 256) { c0l[threadIdx.x] = 0.f; c1l[threadIdx.x] = 0.f; }
    fill_w<640, 128>(ldsL0, p.wih0, p.whh0, j0);
    fill_w<1024, 512>(ldsL1, p.wih1, p.whh1, j0);
    __syncthreads();

    // -------- encoder: L0 and L1 interleaved (L1 lags L0 by LAG steps) -----
    const int LAG = 3;
    for (int r = 0; r < 512 + LAG; ++r) {
        if (r < 512) {
            int t = r;
            wait2(t > 0 ? &cL0[(t - 1) * 4 + m_idx] : nullptr, nullptr);
            lstm_round<640, 128, true>(xf + (size_t)t * B * I, I,
                                       h0all + (size_t)t * B * H, H, false,
                                       ldsL0, b0n0, b0n1, scr, gb, c0l,
                                       h0all + (size_t)(t + 1) * B * H, m_idx, j0);
            arrive(&cL0[t * 4 + m_idx]);
        }
        if (r >= LAG) {
            int t = r - LAG;
            wait2(&cL0[t * 4 + m_idx],
                  t > 0 ? &cL1[(t - 1) * 4 + m_idx] : nullptr);
            lstm_round<1024, 512, false>(h0all + (size_t)(t + 1) * B * H, H,
                                         h1db + (size_t)((t - 1) & 1) * B * H, H, false,
                                         ldsL1, b1n0, b1n1, scr, gb, c1l,
                                         h1db + (size_t)(t & 1) * B * H, m_idx, j0);
            arrive(&cL1[t * 4 + m_idx]);
        }
    }

    // -------- decoder weight fill (LDS aliases enc weights; ours are done) --
    __syncthreads();
    fill_w<1024, 512>(ldsD0, weff, p.whh2, j0);
    fill_w<1024, 512>(ldsD1, p.wih3, p.whh3, j0);
    __syncthreads();
    // NOTE: cell state c0l/c1l carries encoder-final -> decoder (per reference)

    // -------- decoder: closed loop, de0 -> de1 per step ---------------------
    for (int t = 0; t < 512; ++t) {
        if (t == 0) wait2(&cL1[511 * 4 + m_idx], nullptr);
        else        wait2(&cD0[(t - 1) * 4 + m_idx], &cD1[(t - 1) * 4 + m_idx]);
        // de0: A = h1(t-1) via W_eff (zeroed at t=0: inp0 = 0), B = h0_de(t-1)
        lstm_round<1024, 512, false>(
            t == 0 ? (h1db + (size_t)1 * B * H) : (h1st + (size_t)(t - 1) * B * H), H,
            t == 0 ? (h0all + (size_t)512 * B * H) : (ddb + (size_t)((t - 1) & 1) * B * H), H,
            t == 0,
            ldsD0, b2n0, b2n1, scr, gb, c0l,
            ddb + (size_t)(t & 1) * B * H, m_idx, j0);
        arrive(&cD0[t * 4 + m_idx]);

        wait2(&cD0[t * 4 + m_idx],
              t > 0 ? &cD1[(t - 1) * 4 + m_idx] : nullptr);
        // de1: A = h0_de(t), B = h1(t-1)
        lstm_round<1024, 512, false>(
            ddb + (size_t)(t & 1) * B * H, H,
            t == 0 ? (h1db + (size_t)1 * B * H) : (h1st + (size_t)(t - 1) * B * H), H,
            false,
            ldsD1, b3n0, b3n1, scr, gb, c1l,
            h1st + (size_t)t * B * H, m_idx, j0);
        arrive(&cD1[t * 4 + m_idx]);
    }
}

// ===========================================================================
// final: preds[b][t][i] = sum_j h1_store[t][b][j] * W_lin[i][j]   (fp32 out)
// ===========================================================================
__global__ void __launch_bounds__(256) pred_kernel(const f16* __restrict__ h1s,
                                                   const f16* __restrict__ wl,
                                                   float* __restrict__ out) {
    int wg = blockIdx.x;                       // 1024 wgs x 64 rows
    int wv = threadIdx.x >> 6, lane = threadIdx.x & 63;
    int m0 = wg * 64 + wv * 16;
    int arow = m0 + (lane & 15);
    int kk0 = (lane >> 4) * 8;
    f32x4 acc[8];
#pragma unroll
    for (int n = 0; n < 8; ++n) acc[n] = (f32x4){0.f, 0.f, 0.f, 0.f};
#pragma unroll
    for (int ks = 0; ks < 16; ++ks) {
        f16x8 a = *(const f16x8*)(h1s + (size_t)arow * H + ks * 32 + kk0);
#pragma unroll
        for (int n = 0; n < 8; ++n) {
            f16x8 b = *(const f16x8*)(wl + (size_t)(n * 16 + (lane & 15)) * H + ks * 32 + kk0);
            acc[n] = __builtin_amdgcn_mfma_f32_16x16x32_f16(a, b, acc[n], 0, 0, 0);
        }
    }
    int col = lane & 15, r0 = (lane >> 4) * 4;
#pragma unroll
    for (int n = 0; n < 8; ++n)
#pragma unroll
        for (int i = 0; i < 4; ++i) {
            int m = m0 + r0 + i;
            int t = m >> 7, b = m & 127;
            out[((size_t)b * S + t) * I + n * 16 + col] = acc[n][i];
        }
}

// ===========================================================================
extern "C" void kernel_launch(void* const* d_in, const int* in_sizes, int n_in,
                              void* d_out, int out_size, void* d_ws, size_t ws_size,
                              hipStream_t stream) {
    (void)in_sizes; (void)n_in; (void)out_size; (void)ws_size;
    const float* x        = (const float*)d_in[0];
    const float* wih_en0  = (const float*)d_in[1];
    const float* whh_en0  = (const float*)d_in[2];
    const float* bih_en0  = (const float*)d_in[3];
    const float* bhh_en0  = (const float*)d_in[4];
    const float* wih_en1  = (const float*)d_in[5];
    const float* whh_en1  = (const float*)d_in[6];
    const float* bih_en1  = (const float*)d_in[7];
    const float* bhh_en1  = (const float*)d_in[8];
    const float* wih_de0  = (const float*)d_in[9];
    const float* whh_de0  = (const float*)d_in[10];
    const float* bih_de0  = (const float*)d_in[11];
    const float* bhh_de0  = (const float*)d_in[12];
    const float* wih_de1  = (const float*)d_in[13];
    const float* whh_de1  = (const float*)d_in[14];
    const float* bih_de1  = (const float*)d_in[15];
    const float* bhh_de1  = (const float*)d_in[16];
    const float* wlin     = (const float*)d_in[17];
    char* ws = (char*)d_ws;

    hipMemsetAsync(ws, 0, ZERO_BYTES, stream);
    prep_kernel<<<2048, 256, 0, stream>>>(x, bih_en0, bhh_en0, bih_en1, bhh_en1,
                                          bih_de0, bhh_de0, bih_de1, bhh_de1,
                                          wlin, ws);
    weff_kernel<<<4096, 256, 0, stream>>>(wih_de0, wlin, ws);

    hipFuncSetAttribute((const void*)lstm_persistent,
                        hipFuncAttributeMaxDynamicSharedMemorySize, SMEM_BYTES);
    PParams p{wih_en0, whh_en0, wih_en1, whh_en1, whh_de0, wih_de1, whh_de1, ws};
    void* args[] = {&p};
    hipLaunchCooperativeKernel((const void*)lstm_persistent, dim3(256), dim3(512),
                               args, SMEM_BYTES, stream);

    pred_kernel<<<1024, 256, 0, stream>>>((const f16*)(ws + OFF_H1ST),
                                          (const f16*)(ws + OFF_WLIN16),
                                          (float*)d_out);
}

// Round 4
// 11626.055 us; speedup vs baseline: 4.7225x; 1.1404x over previous
//
#include <hip/hip_runtime.h>
#include <hip/hip_fp16.h>

// ---------------------------------------------------------------------------
// LSTM autoencoder (B=128,S=512,I=128,H=512), persistent-RNN, round 3 resubmit
// (round 3 bench never ran: GPU acquisition timeout; kernel unchanged):
//  - per-producer timestamp flags (plain sc0sc1 dword stores), consumer polls
//    64 flags with ONE coalesced 64-lane load + __all  (no atomic convoy)
//  - encoder split across wg halves: wgs 0..127 run L0 chain (64 rows x 8
//    h-cols each), wgs 128..255 run L1 chain; L1 self-paces behind L0.
//    Encoder critical path: 512 rounds (was 1024).
//  - write-once buffers (xf, h0all, h1st) read with PLAIN cached loads (L2
//    serves the 64-reader broadcast); double-buffered h1db/ddb + flags +
//    c-handoff stay sc0sc1 (MALL-coherent).
//  - decoder: all 256 wgs, 32 rows x 8 h-cols, de0/de1 chained via flags.
//  - W_lin folded into de0 (W_eff); preds = one big GEMM at the end.
// ---------------------------------------------------------------------------

#define DEVINL __device__ __forceinline__

typedef _Float16 f16;
typedef _Float16 f16x8 __attribute__((ext_vector_type(8)));
typedef float    f32x4 __attribute__((ext_vector_type(4)));

constexpr int B = 128, S = 512, I = 128, H = 512, G4 = 4 * H; // G4 = 2048

// ---- d_ws layout (bytes) ----
constexpr size_t OFF_FLAGS  = 0;          // fL0[2][64] fL1[2][64] fD0[4][64] fD1[4][64]
constexpr size_t OFF_H1DBUF = 32768;      // [2][128][512] f16        262144
constexpr size_t OFF_C0G    = 294912;     // [128][512] f32 handoff   262144
constexpr size_t OFF_C1G    = 557056;     // [128][512] f32 handoff   262144
constexpr size_t OFF_H0ALL  = 819200;     // [513][128][512] f16      67239936
constexpr size_t OFF_DDBUF  = 68059136;   // [2][128][512] f16        262144
constexpr size_t OFF_H1ST   = 68321280;   // [512][128][512] f16      67108864
constexpr size_t OFF_XF16   = 135430144;  // [512][128][128] f16      16777216
constexpr size_t OFF_WLIN16 = 152207360;  // [128][512] f16           131072
constexpr size_t OFF_BSUM   = 152338432;  // [4][2048] f32            32768
constexpr size_t OFF_WEFF   = 152371200;  // [2048][512] f32          4194304
constexpr size_t ZERO_BYTES = 950272;     // flags + h1db + c0g + c1g + h0all slot0

// ---- LDS layout (158976 B total, fits 160 KiB) ----
constexpr int LDS_W0   = 0;       // enc layer weights / dec D0 (<=65536)
constexpr int LDS_W1   = 65536;   // dec D1                      65536
constexpr int LDS_SCR  = 131072;  // reduction scratch           15360
constexpr int LDS_GB   = 146432;  // [64][33] f32 gates           8448
constexpr int LDS_CA   = 154880;  // [512] f32 cell (enc own / dec c0)
constexpr int LDS_CB   = 156928;  // [512] f32 cell (dec c1)
constexpr int SMEM_BYTES = 158976;

// ---------------------------------------------------------------------------
// coherent (MALL) helpers. All sc0|sc1 ops are inline asm; one manual
// s_waitcnt vmcnt(0) drains before any flag publication.
// ---------------------------------------------------------------------------
DEVINL void cload(f16x8& r, const f16* p) {
    asm volatile("global_load_dwordx4 %0, %1, off sc0 sc1" : "=v"(r) : "v"(p));
}
DEVINL void cload_f32(float& r, const float* p) {
    asm volatile("global_load_dword %0, %1, off sc0 sc1" : "=v"(r) : "v"(p));
}
DEVINL void cstore_h(f16* p, unsigned v) {
    asm volatile("global_store_short %0, %1, off sc0 sc1" :: "v"(p), "v"(v));
}
DEVINL void cstore_f32(float* p, float v) {
    asm volatile("global_store_dword %0, %1, off sc0 sc1" :: "v"(p), "v"(v));
}
DEVINL void drain_vm() {
    asm volatile("s_waitcnt vmcnt(0)" ::: "memory");
    __builtin_amdgcn_sched_barrier(0);
}

// ===========================================================================
// prep: x transpose-convert, W_lin convert, bias sums
// ===========================================================================
__global__ void prep_kernel(const float* __restrict__ x,
                            const float* b0a, const float* b0b,
                            const float* b1a, const float* b1b,
                            const float* b2a, const float* b2b,
                            const float* b3a, const float* b3b,
                            const float* __restrict__ wlin, char* ws) {
    f16*   xf = (f16*)(ws + OFF_XF16);
    f16*   wl = (f16*)(ws + OFF_WLIN16);
    float* bs = (float*)(ws + OFF_BSUM);
    int tid = blockIdx.x * blockDim.x + threadIdx.x;
    int nth = gridDim.x * blockDim.x;
    for (int idx = tid; idx < S * B * I; idx += nth) {
        int i = idx & 127, b = (idx >> 7) & 127, t = idx >> 14;
        xf[idx] = (f16)x[((size_t)b * S + t) * I + i];   // [t][b][i] <- [b][t][i]
    }
    for (int idx = tid; idx < I * H; idx += nth) wl[idx] = (f16)wlin[idx];
    for (int idx = tid; idx < G4; idx += nth) {
        bs[idx]          = b0a[idx] + b0b[idx];
        bs[G4 + idx]     = b1a[idx] + b1b[idx];
        bs[2 * G4 + idx] = b2a[idx] + b2b[idx];
        bs[3 * G4 + idx] = b3a[idx] + b3b[idx];
    }
}

// ===========================================================================
// W_eff = W_ih_de0 [2048,128] @ W_lin [128,512]  -> [2048,512] fp32
// ===========================================================================
__global__ void weff_kernel(const float* __restrict__ wih_de0,
                            const float* __restrict__ wlin, char* ws) {
    float* weff = (float*)(ws + OFF_WEFF);
    int e  = blockIdx.x * 256 + threadIdx.x;
    int gc = e >> 9, k = e & 511;
    float acc = 0.f;
    for (int i = 0; i < I; ++i) acc += wih_de0[gc * I + i] * wlin[i * H + k];
    weff[e] = acc;
}

// ===========================================================================
// persistent kernel helpers
// ===========================================================================
struct PParams {
    const float *wih0, *whh0, *wih1, *whh1, *whh2, *wih3, *whh3;
    char* ws;
};

// wave 0 polls flag set A, wave 1 polls flag set B; caller __syncthreads().
// Each poll iteration: ONE coalesced 64-lane dword load + __all reduce.
DEVINL void waitA(const unsigned* f, unsigned tgt) {
    if (f && threadIdx.x < 64) {
        unsigned v;
        do {
            v = __hip_atomic_load(f + (threadIdx.x & 63),
                                  __ATOMIC_RELAXED, __HIP_MEMORY_SCOPE_AGENT);
        } while (!__all((int)(v >= tgt)));
    }
}
DEVINL void waitB(const unsigned* f, unsigned tgt) {
    if (f && threadIdx.x >= 64 && threadIdx.x < 128) {
        unsigned v;
        do {
            v = __hip_atomic_load(f + (threadIdx.x & 63),
                                  __ATOMIC_RELAXED, __HIP_MEMORY_SCOPE_AGENT);
        } while (!__all((int)(v >= tgt)));
    }
}

// publish: drain all this-wg stores to the coherence point, join waves,
// then ONE plain timestamp store to this wg's own flag word (no atomics).
DEVINL void arrive(unsigned* f, unsigned val) {
    drain_vm();
    __syncthreads();
    if (threadIdx.x == 0)
        __hip_atomic_store(f, val, __ATOMIC_RELAXED, __HIP_MEMORY_SCOPE_AGENT);
}

// Fill LDS weight block: layout [ntile][K/32][lane64][8 f16] so the B-fragment
// ds_read_b128 is lane-linear (conflict-free). col c in [0,32): gate=c>>3,
// j=c&7 -> global gate row gcol = gate*512 + j0 + j.
template <int K, int SPLIT>
DEVINL void fill_w(f16* ldsW, const float* __restrict__ matA,
                   const float* __restrict__ matB, int j0) {
    for (int idx = threadIdx.x; idx < 32 * K; idx += 512) {
        int c = idx / K, k = idx - c * K;
        int gcol = ((c >> 3) << 9) + j0 + (c & 7);
        float w = (k < SPLIT) ? matA[(size_t)gcol * SPLIT + k]
                              : matB[(size_t)gcol * (K - SPLIT) + (k - SPLIT)];
        int nt = c >> 4, lane = (((k >> 3) & 3) << 4) | (c & 15);
        int ks = k >> 5, j = k & 7;
        ldsW[(((size_t)nt * (K / 32) + ks) * 64 + lane) * 8 + j] = (f16)w;
    }
}

// One recurrence round, generalized:
//   MT m-tiles (16 rows each), KP K-partitions; MT*KP == 8 waves.
//   AMODE/BMODE: 0 = plain cached load (write-once buffers), 1 = sc0sc1.
// Each wave computes BOTH n-tiles. KP-way partial reduce in LDS, gate
// exchange, fused LSTM cell update (c in LDS), coherent h store.
template <int K, int SPLIT, int MT, int KP, int AMODE, int BMODE>
DEVINL void lstm_round(const f16* __restrict__ actA, int strA,
                       const f16* __restrict__ actB, int strB, bool skipA,
                       const f16* __restrict__ ldsW, float biasN0, float biasN1,
                       float* scr, float* gb, float* c_lds,
                       f16* __restrict__ hdst, int row0, int j0) {
    const int tid = threadIdx.x;
    const int wv = tid >> 6, lane = tid & 63;
    const int m_t = wv / KP, k_p = wv % KP;
    const int row = row0 + m_t * 16 + (lane & 15);
    const int kk0 = (lane >> 4) * 8;
    constexpr int KS = K / 32;
    constexpr int SQ = KS / KP;
    const int ks0 = k_p * SQ;
    const f16* pa = actA + (size_t)row * strA + kk0;
    const f16* pb = actB + (size_t)row * strB + kk0 - SPLIT;

    f16x8 areg[SQ];
#pragma unroll
    for (int s = 0; s < SQ; ++s) {
        int kbase = (ks0 + s) * 32;
        if (kbase < SPLIT) {
            if (skipA) {
#pragma unroll
                for (int q = 0; q < 8; ++q) areg[s][q] = (f16)0;
            } else if (AMODE == 0) areg[s] = *(const f16x8*)(pa + kbase);
            else                   cload(areg[s], pa + kbase);
        } else {
            if (BMODE == 0) areg[s] = *(const f16x8*)(pb + kbase);
            else            cload(areg[s], pb + kbase);
        }
    }
    drain_vm();

    f32x4 acc0 = (k_p == 0) ? (f32x4){biasN0, biasN0, biasN0, biasN0}
                            : (f32x4){0.f, 0.f, 0.f, 0.f};
    f32x4 acc1 = (k_p == 0) ? (f32x4){biasN1, biasN1, biasN1, biasN1}
                            : (f32x4){0.f, 0.f, 0.f, 0.f};
#pragma unroll
    for (int s = 0; s < SQ; ++s) {
        int ks = ks0 + s;
        f16x8 b0 = *(const f16x8*)(ldsW + (size_t)(ks * 64 + lane) * 8);
        f16x8 b1 = *(const f16x8*)(ldsW + (size_t)((KS + ks) * 64 + lane) * 8);
        acc0 = __builtin_amdgcn_mfma_f32_16x16x32_f16(areg[s], b0, acc0, 0, 0, 0);
        acc1 = __builtin_amdgcn_mfma_f32_16x16x32_f16(areg[s], b1, acc1, 0, 0, 0);
    }

    const int col = lane & 15, r0 = (lane >> 4) * 4;
    if (k_p) {  // partials -> scr (stride 20: 16B-aligned, 2-way banks = free)
        *(f32x4*)(scr + ((m_t * 2 + 0) * (KP - 1) + (k_p - 1)) * 320 + col * 20 + r0) = acc0;
        *(f32x4*)(scr + ((m_t * 2 + 1) * (KP - 1) + (k_p - 1)) * 320 + col * 20 + r0) = acc1;
    }
    __syncthreads();
    if (k_p == 0) {
#pragma unroll
        for (int part = 0; part < KP - 1; ++part) {
            acc0 += *(const f32x4*)(scr + ((m_t * 2 + 0) * (KP - 1) + part) * 320 + col * 20 + r0);
            acc1 += *(const f32x4*)(scr + ((m_t * 2 + 1) * (KP - 1) + part) * 320 + col * 20 + r0);
        }
#pragma unroll
        for (int i = 0; i < 4; ++i) {
            gb[(m_t * 16 + r0 + i) * 33 + col]      = acc0[i];
            gb[(m_t * 16 + r0 + i) * 33 + 16 + col] = acc1[i];
        }
    }
    __syncthreads();
    if (tid < MT * 128) {  // cell update: MT*16 rows x 8 h-cols, c in LDS
        int r = tid >> 3, jj = tid & 7;
        const float* grow = gb + r * 33;
        float gi = grow[jj], gf = grow[8 + jj], gg = grow[16 + jj], go = grow[24 + jj];
        float si = 1.f / (1.f + __expf(-gi));
        float sf = 1.f / (1.f + __expf(-gf));
        float so = 1.f / (1.f + __expf(-go));
        float tg = tanhf(gg);
        float cn = sf * c_lds[tid] + si * tg;
        c_lds[tid] = cn;
        union { f16 h; unsigned short u; } cvt;
        cvt.h = (f16)(so * tanhf(cn));
        cstore_h(hdst + (size_t)(row0 + r) * H + j0 + jj, (unsigned)cvt.u);
    }
    // arrive (drain + barrier + flag) done by caller
}

// ===========================================================================
// the persistent cooperative kernel
// ===========================================================================
__global__ void __launch_bounds__(512, 1) lstm_persistent(PParams p) {
    extern __shared__ char smem[];
    char* ws = p.ws;
    unsigned* flg = (unsigned*)(ws + OFF_FLAGS);
    unsigned* fL0 = flg;            // [2][64]
    unsigned* fL1 = flg + 128;      // [2][64]
    unsigned* fD0 = flg + 256;      // [4][64]
    unsigned* fD1 = flg + 512;      // [4][64]
    f16*   h1db = (f16*)(ws + OFF_H1DBUF);
    float* c0g  = (float*)(ws + OFF_C0G);
    float* c1g  = (float*)(ws + OFF_C1G);
    f16*   h0all= (f16*)(ws + OFF_H0ALL);
    f16*   ddb  = (f16*)(ws + OFF_DDBUF);
    f16*   h1st = (f16*)(ws + OFF_H1ST);
    const f16*   xf   = (const f16*)(ws + OFF_XF16);
    const float* bs   = (const float*)(ws + OFF_BSUM);
    const float* weff = (const float*)(ws + OFF_WEFF);

    const int wg = blockIdx.x;
    const bool isL0 = wg < 128;
    const int mh = (wg & 127) >> 6;   // encoder 64-row group (0/1)
    const int m  = wg >> 6;           // decoder 32-row group (0..3)
    const int n_idx = wg & 63;
    const int j0 = n_idx * 8;
    const int tid = threadIdx.x, lane = tid & 63;

    int c0col = lane & 15, c1col = 16 + (lane & 15);
    int g0 = ((c0col >> 3) << 9) + j0 + (c0col & 7);
    int g1 = ((c1col >> 3) << 9) + j0 + (c1col & 7);
    float b0n0 = bs[g0],          b0n1 = bs[g1];
    float b1n0 = bs[G4 + g0],     b1n1 = bs[G4 + g1];
    float b2n0 = bs[2 * G4 + g0], b2n1 = bs[2 * G4 + g1];
    float b3n0 = bs[3 * G4 + g0], b3n1 = bs[3 * G4 + g1];

    f16* ldsW0 = (f16*)(smem + LDS_W0);
    f16* ldsW1 = (f16*)(smem + LDS_W1);
    float* scr = (float*)(smem + LDS_SCR);
    float* gb  = (float*)(smem + LDS_GB);
    float* cA  = (float*)(smem + LDS_CA);
    float* cB  = (float*)(smem + LDS_CB);

    // ======================= encoder (layer-split) ========================
    if (isL0) {
        fill_w<640, 128>(ldsW0, p.wih0, p.whh0, j0);
        cA[tid] = 0.f;
        __syncthreads();
        for (int t = 0; t < 512; ++t) {
            waitA(t > 0 ? &fL0[mh * 64] : nullptr, (unsigned)t);
            __syncthreads();
            lstm_round<640, 128, 4, 2, 0, 0>(
                xf + (size_t)t * B * I, I,
                h0all + (size_t)t * B * H, H, false,
                ldsW0, b0n0, b0n1, scr, gb, cA,
                h0all + (size_t)(t + 1) * B * H, mh * 64, j0);
            if (t == 511)  // final c0 handoff (drained by the same arrive)
                cstore_f32(&c0g[(size_t)(mh * 64 + (tid >> 3)) * H + j0 + (tid & 7)], cA[tid]);
            arrive(&fL0[mh * 64 + n_idx], (unsigned)(t + 1));
        }
    } else {
        fill_w<1024, 512>(ldsW0, p.wih1, p.whh1, j0);
        cA[tid] = 0.f;
        __syncthreads();
        for (int t = 0; t < 512; ++t) {
            waitA(&fL0[mh * 64], (unsigned)(t + 1));
            waitB(t > 0 ? &fL1[mh * 64] : nullptr, (unsigned)t);
            __syncthreads();
            lstm_round<1024, 512, 4, 2, 0, 1>(
                h0all + (size_t)(t + 1) * B * H, H,
                h1db + (size_t)((t - 1) & 1) * B * H, H, false,
                ldsW0, b1n0, b1n1, scr, gb, cA,
                h1db + (size_t)(t & 1) * B * H, mh * 64, j0);
            if (t == 511)
                cstore_f32(&c1g[(size_t)(mh * 64 + (tid >> 3)) * H + j0 + (tid & 7)], cA[tid]);
            arrive(&fL1[mh * 64 + n_idx], (unsigned)(t + 1));
        }
    }

    // ===================== decoder (all 256 wgs) ==========================
    __syncthreads();
    fill_w<1024, 512>(ldsW0, weff, p.whh2, j0);     // de0: [W_eff | W_hh_de0]
    fill_w<1024, 512>(ldsW1, p.wih3, p.whh3, j0);   // de1: [W_ih  | W_hh]
    waitA(&fL0[(m >> 1) * 64], 512u);
    waitB(&fL1[(m >> 1) * 64], 512u);
    __syncthreads();
    {   // load carried cell state (32 rows x 8 cols each layer)
        int r = (tid & 255) >> 3, jj = tid & 7;
        float v;
        cload_f32(v, (tid < 256 ? c0g : c1g) + (size_t)(m * 32 + r) * H + j0 + jj);
        asm volatile("s_waitcnt vmcnt(0)" ::: "memory");
        (tid < 256 ? cA : cB)[tid & 255] = v;
    }
    __syncthreads();

    for (int t = 0; t < 512; ++t) {
        if (t > 0) {
            waitA(&fD0[m * 64], (unsigned)t);
            waitB(&fD1[m * 64], (unsigned)t);
            __syncthreads();
        }
        // ---- de0: A = h1(t-1) via W_eff (zero at t=0), B = h0_de(t-1) ----
        if (t == 0)
            lstm_round<1024, 512, 2, 4, 0, 0>(
                h1db, H,                                  // unused (skipA)
                h0all + (size_t)512 * B * H, H, true,     // enc h0 final (plain)
                ldsW0, b2n0, b2n1, scr, gb, cA,
                ddb, m * 32, j0);
        else
            lstm_round<1024, 512, 2, 4, 0, 1>(
                h1st + (size_t)(t - 1) * B * H, H,        // write-once (plain)
                ddb + (size_t)((t - 1) & 1) * B * H, H, false,  // dbuf (sc)
                ldsW0, b2n0, b2n1, scr, gb, cA,
                ddb + (size_t)(t & 1) * B * H, m * 32, j0);
        arrive(&fD0[m * 64 + n_idx], (unsigned)(t + 1));

        waitA(&fD0[m * 64], (unsigned)(t + 1));
        __syncthreads();
        // ---- de1: A = h0_de(t), B = h1(t-1) ------------------------------
        if (t == 0)
            lstm_round<1024, 512, 2, 4, 1, 1>(
                ddb, H,                                   // dbuf (sc)
                h1db + (size_t)B * H, H, false,           // enc h1 final (sc dbuf)
                ldsW1, b3n0, b3n1, scr, gb, cB,
                h1st, m * 32, j0);
        else
            lstm_round<1024, 512, 2, 4, 1, 0>(
                ddb + (size_t)(t & 1) * B * H, H,         // dbuf (sc)
                h1st + (size_t)(t - 1) * B * H, H, false, // write-once (plain)
                ldsW1, b3n0, b3n1, scr, gb, cB,
                h1st + (size_t)t * B * H, m * 32, j0);
        arrive(&fD1[m * 64 + n_idx], (unsigned)(t + 1));
    }
}

// ===========================================================================
// final: preds[b][t][i] = sum_j h1_store[t][b][j] * W_lin[i][j]   (fp32 out)
// ===========================================================================
__global__ void __launch_bounds__(256) pred_kernel(const f16* __restrict__ h1s,
                                                   const f16* __restrict__ wl,
                                                   float* __restrict__ out) {
    int wg = blockIdx.x;                       // 1024 wgs x 64 rows
    int wv = threadIdx.x >> 6, lane = threadIdx.x & 63;
    int m0 = wg * 64 + wv * 16;
    int arow = m0 + (lane & 15);
    int kk0 = (lane >> 4) * 8;
    f32x4 acc[8];
#pragma unroll
    for (int n = 0; n < 8; ++n) acc[n] = (f32x4){0.f, 0.f, 0.f, 0.f};
#pragma unroll
    for (int ks = 0; ks < 16; ++ks) {
        f16x8 a = *(const f16x8*)(h1s + (size_t)arow * H + ks * 32 + kk0);
#pragma unroll
        for (int n = 0; n < 8; ++n) {
            f16x8 b = *(const f16x8*)(wl + (size_t)(n * 16 + (lane & 15)) * H + ks * 32 + kk0);
            acc[n] = __builtin_amdgcn_mfma_f32_16x16x32_f16(a, b, acc[n], 0, 0, 0);
        }
    }
    int col = lane & 15, r0 = (lane >> 4) * 4;
#pragma unroll
    for (int n = 0; n < 8; ++n)
#pragma unroll
        for (int i = 0; i < 4; ++i) {
            int mm = m0 + r0 + i;
            int t = mm >> 7, b = mm & 127;
            out[((size_t)b * S + t) * I + n * 16 + col] = acc[n][i];
        }
}

// ===========================================================================
extern "C" void kernel_launch(void* const* d_in, const int* in_sizes, int n_in,
                              void* d_out, int out_size, void* d_ws, size_t ws_size,
                              hipStream_t stream) {
    (void)in_sizes; (void)n_in; (void)out_size; (void)ws_size;
    const float* x        = (const float*)d_in[0];
    const float* wih_en0  = (const float*)d_in[1];
    const float* whh_en0  = (const float*)d_in[2];
    const float* bih_en0  = (const float*)d_in[3];
    const float* bhh_en0  = (const float*)d_in[4];
    const float* wih_en1  = (const float*)d_in[5];
    const float* whh_en1  = (const float*)d_in[6];
    const float* bih_en1  = (const float*)d_in[7];
    const float* bhh_en1  = (const float*)d_in[8];
    const float* wih_de0  = (const float*)d_in[9];
    const float* whh_de0  = (const float*)d_in[10];
    const float* bih_de0  = (const float*)d_in[11];
    const float* bhh_de0  = (const float*)d_in[12];
    const float* wih_de1  = (const float*)d_in[13];
    const float* whh_de1  = (const float*)d_in[14];
    const float* bih_de1  = (const float*)d_in[15];
    const float* bhh_de1  = (const float*)d_in[16];
    const float* wlin     = (const float*)d_in[17];
    char* ws = (char*)d_ws;

    hipMemsetAsync(ws, 0, ZERO_BYTES, stream);
    prep_kernel<<<2048, 256, 0, stream>>>(x, bih_en0, bhh_en0, bih_en1, bhh_en1,
                                          bih_de0, bhh_de0, bih_de1, bhh_de1,
                                          wlin, ws);
    weff_kernel<<<4096, 256, 0, stream>>>(wih_de0, wlin, ws);

    hipFuncSetAttribute((const void*)lstm_persistent,
                        hipFuncAttributeMaxDynamicSharedMemorySize, SMEM_BYTES);
    PParams p{wih_en0, whh_en0, wih_en1, whh_en1, whh_de0, wih_de1, whh_de1, ws};
    void* args[] = {&p};
    hipLaunchCooperativeKernel((const void*)lstm_persistent, dim3(256), dim3(512),
                               args, SMEM_BYTES, stream);

    pred_kernel<<<1024, 256, 0, stream>>>((const f16*)(ws + OFF_H1ST),
                                          (const f16*)(ws + OFF_WLIN16),
                                          (float*)d_out);
}